// Round 1
// baseline (103.392 us; speedup 1.0000x reference)
//
#include <hip/hip_runtime.h>

typedef __attribute__((ext_vector_type(8))) short short8;
typedef __attribute__((ext_vector_type(4))) float f32x4;

__device__ __forceinline__ short f2bf(float x) {
  unsigned u = __float_as_uint(x);
  unsigned r = (u + 0x7FFFu + ((u >> 16) & 1u)) >> 16;  // RNE
  return (short)r;
}

// One block per batch element b. 256 threads = 4 waves.
// Phase 2: A = state@Wtop + gb0, C = state@Wbot  (bf16 MFMA, fp32 acc -> LDS)
// Phase 3: for all 240 ordered pairs, u = relu(A_i + C_j), V = u @ gW1 (MFMA),
//          pooled += relu(V + gb1)
// Phase 4: fused fp32 f-MLP GEMV -> out[b]
__global__ __launch_bounds__(256) void pair_mlp_kernel(
    const float* __restrict__ state,
    const float* __restrict__ gW0, const float* __restrict__ gb0,
    const float* __restrict__ gW1, const float* __restrict__ gb1,
    const float* __restrict__ fW0, const float* __restrict__ fb0,
    const float* __restrict__ fW1, const float* __restrict__ fb1,
    float* __restrict__ out)
{
  const int b   = blockIdx.x;
  const int tid = threadIdx.x;
  const int w   = tid >> 6;   // wave 0..3
  const int l   = tid & 63;
  const int lr  = l & 15;     // fragment row/col
  const int lg  = l >> 4;     // k-group 0..3

  // 260-f32 row stride: bank offset 4*row -> <=2-way conflict (free)
  __shared__ float A_lds[16][260];
  __shared__ float C_lds[16][260];
  __shared__ float pooled_lds[256];
  __shared__ float h1_lds[256];

  const float* stb = state + (size_t)b * (16 * 128);

  // ---------------- Phase 2: [A|C] = state[16x128] @ gW0[128x512] ----------------
  // A-fragments: row = lr (s), k = kk*32 + lg*8 + e  (d index)
  short8 sfrag[4];
  #pragma unroll
  for (int kk = 0; kk < 4; ++kk) {
    const float* sp = stb + lr * 128 + kk * 32 + lg * 8;
    f32x4 s0 = *(const f32x4*)sp;
    f32x4 s1 = *(const f32x4*)(sp + 4);
    short8 f;
    f[0] = f2bf(s0[0]); f[1] = f2bf(s0[1]); f[2] = f2bf(s0[2]); f[3] = f2bf(s0[3]);
    f[4] = f2bf(s1[0]); f[5] = f2bf(s1[1]); f[6] = f2bf(s1[2]); f[7] = f2bf(s1[3]);
    sfrag[kk] = f;
  }

  const f32x4 zero4 = {0.f, 0.f, 0.f, 0.f};
  f32x4 acc2[8];
  #pragma unroll
  for (int nt = 0; nt < 8; ++nt) acc2[nt] = zero4;

  // wave w owns output cols [128w, 128w+128) of the 512-wide [A|C]
  #pragma unroll
  for (int nt = 0; nt < 8; ++nt) {
    const int col512 = 128 * w + 16 * nt + lr;
    const int isA    = (col512 < 256);
    const int wcol   = isA ? col512 : (col512 - 256);
    const int rbase  = isA ? 0 : 128;           // Wtop rows 0..127, Wbot rows 128..255
    #pragma unroll
    for (int kk = 0; kk < 4; ++kk) {
      const int k0 = rbase + kk * 32 + lg * 8;
      short8 bf;
      #pragma unroll
      for (int e = 0; e < 8; ++e)
        bf[e] = f2bf(gW0[(size_t)(k0 + e) * 256 + wcol]);
      acc2[nt] = __builtin_amdgcn_mfma_f32_16x16x32_bf16(sfrag[kk], bf, acc2[nt], 0, 0, 0);
    }
  }

  // store to LDS; C/D layout: col = lr, row = lg*4 + r  (m89-verified)
  #pragma unroll
  for (int nt = 0; nt < 8; ++nt) {
    const int col512 = 128 * w + 16 * nt + lr;
    #pragma unroll
    for (int r = 0; r < 4; ++r) {
      const int row = lg * 4 + r;
      float v = acc2[nt][r];
      if (col512 < 256) A_lds[row][col512]       = v + gb0[col512];
      else              C_lds[row][col512 - 256] = v;
    }
  }

  // ---------------- preload gW1 fragments into registers (128 VGPR/lane) ----------
  // wave w owns N-cols [64w, 64w+64): 4 subtiles x 8 K-steps
  short8 bw[4][8];
  #pragma unroll
  for (int nt = 0; nt < 4; ++nt) {
    const int n = 64 * w + 16 * nt + lr;
    #pragma unroll
    for (int kk = 0; kk < 8; ++kk) {
      const int k0 = kk * 32 + lg * 8;
      short8 f;
      #pragma unroll
      for (int e = 0; e < 8; ++e)
        f[e] = f2bf(gW1[(size_t)(k0 + e) * 256 + n]);
      bw[nt][kk] = f;
    }
  }

  float gb1v[4];
  #pragma unroll
  for (int nt = 0; nt < 4; ++nt) gb1v[nt] = gb1[64 * w + 16 * nt + lr];

  __syncthreads();

  // ---------------- Phase 3: pair loop, 15 M-tiles of 16 pairs --------------------
  float pooled_part[4] = {0.f, 0.f, 0.f, 0.f};
  #pragma unroll 1
  for (int m = 0; m < 15; ++m) {
    // ordered pair for row p: i = p/15, j skips i
    const int p  = m * 16 + lr;
    const int i  = p / 15;
    const int rr = p - i * 15;
    const int j  = rr + (rr >= i ? 1 : 0);

    f32x4 acc[4];
    #pragma unroll
    for (int nt = 0; nt < 4; ++nt) acc[nt] = zero4;

    #pragma unroll
    for (int kk = 0; kk < 8; ++kk) {
      const int k0 = kk * 32 + lg * 8;
      f32x4 a0 = *(const f32x4*)&A_lds[i][k0];
      f32x4 a1 = *(const f32x4*)&A_lds[i][k0 + 4];
      f32x4 c0 = *(const f32x4*)&C_lds[j][k0];
      f32x4 c1 = *(const f32x4*)&C_lds[j][k0 + 4];
      short8 u;
      u[0] = f2bf(fmaxf(a0[0] + c0[0], 0.f));
      u[1] = f2bf(fmaxf(a0[1] + c0[1], 0.f));
      u[2] = f2bf(fmaxf(a0[2] + c0[2], 0.f));
      u[3] = f2bf(fmaxf(a0[3] + c0[3], 0.f));
      u[4] = f2bf(fmaxf(a1[0] + c1[0], 0.f));
      u[5] = f2bf(fmaxf(a1[1] + c1[1], 0.f));
      u[6] = f2bf(fmaxf(a1[2] + c1[2], 0.f));
      u[7] = f2bf(fmaxf(a1[3] + c1[3], 0.f));
      #pragma unroll
      for (int nt = 0; nt < 4; ++nt)
        acc[nt] = __builtin_amdgcn_mfma_f32_16x16x32_bf16(u, bw[nt][kk], acc[nt], 0, 0, 0);
    }

    // relu + bias, accumulate pooled (rows of V = pairs; sum them all)
    #pragma unroll
    for (int nt = 0; nt < 4; ++nt) {
      #pragma unroll
      for (int r = 0; r < 4; ++r)
        pooled_part[nt] += fmaxf(acc[nt][r] + gb1v[nt], 0.f);
    }
  }

  // reduce across the 4 lane-groups holding disjoint row subsets of the same col
  #pragma unroll
  for (int nt = 0; nt < 4; ++nt) {
    float v = pooled_part[nt];
    v += __shfl_xor(v, 16);
    v += __shfl_xor(v, 32);
    if (lg == 0) pooled_lds[64 * w + 16 * nt + lr] = v;
  }
  __syncthreads();

  // ---------------- Phase 4: f-MLP in fp32 (GEMV per batch) -----------------------
  {
    float a0 = 0.f, a1 = 0.f, a2 = 0.f, a3 = 0.f;
    #pragma unroll 4
    for (int k = 0; k < 256; k += 4) {
      a0 += pooled_lds[k + 0] * fW0[(size_t)(k + 0) * 256 + tid];
      a1 += pooled_lds[k + 1] * fW0[(size_t)(k + 1) * 256 + tid];
      a2 += pooled_lds[k + 2] * fW0[(size_t)(k + 2) * 256 + tid];
      a3 += pooled_lds[k + 3] * fW0[(size_t)(k + 3) * 256 + tid];
    }
    h1_lds[tid] = fmaxf(fb0[tid] + ((a0 + a1) + (a2 + a3)), 0.f);
  }
  __syncthreads();
  {
    float a0 = 0.f, a1 = 0.f, a2 = 0.f, a3 = 0.f;
    #pragma unroll 4
    for (int k = 0; k < 256; k += 4) {
      a0 += h1_lds[k + 0] * fW1[(size_t)(k + 0) * 256 + tid];
      a1 += h1_lds[k + 1] * fW1[(size_t)(k + 1) * 256 + tid];
      a2 += h1_lds[k + 2] * fW1[(size_t)(k + 2) * 256 + tid];
      a3 += h1_lds[k + 3] * fW1[(size_t)(k + 3) * 256 + tid];
    }
    out[(size_t)b * 256 + tid] = fmaxf(fb1[tid] + ((a0 + a1) + (a2 + a3)), 0.f);
  }
}

extern "C" void kernel_launch(void* const* d_in, const int* in_sizes, int n_in,
                              void* d_out, int out_size, void* d_ws, size_t ws_size,
                              hipStream_t stream) {
  const float* state = (const float*)d_in[0];
  const float* gW0   = (const float*)d_in[1];
  const float* gb0   = (const float*)d_in[2];
  const float* gW1   = (const float*)d_in[3];
  const float* gb1   = (const float*)d_in[4];
  const float* fW0   = (const float*)d_in[5];
  const float* fb0   = (const float*)d_in[6];
  const float* fW1   = (const float*)d_in[7];
  const float* fb1   = (const float*)d_in[8];
  float* out = (float*)d_out;

  const int Bn = in_sizes[0] / (16 * 128);  // 1024
  pair_mlp_kernel<<<dim3(Bn), dim3(256), 0, stream>>>(
      state, gW0, gb0, gW1, gb1, fW0, fb0, fW1, fb1, out);
}

// Round 2
// 101.328 us; speedup vs baseline: 1.0204x; 1.0204x over previous
//
#include <hip/hip_runtime.h>
#include <hip/hip_bf16.h>

typedef __attribute__((ext_vector_type(8))) short short8;
typedef __attribute__((ext_vector_type(4))) float f32x4;

#define LSTR 268  // LDS row stride in f32: 1072B rows -> 16B-aligned, 2-way banks max

__device__ __forceinline__ unsigned short f2bf_rne(float x) {
  unsigned u = __float_as_uint(x);
  return (unsigned short)((u + 0x7FFFu + ((u >> 16) & 1u)) >> 16);
}

// compiler-friendly scalar cast -> fuses to v_cvt_pk_bf16_f32 in pairs (m240)
__device__ __forceinline__ short bfc(float x) {
  __hip_bfloat16 h = __float2bfloat16(x);
  return __builtin_bit_cast(short, h);
}

// ---- prep: weights -> bf16, fragment-transposed into d_ws (once per launch) ----
// W0T[c][k], c in [0,512) = [A|C] output col, k in [0,128): bf16 of
//   gW0[(k + (c>=256 ? 128 : 0))*256 + (c&255)]
// W1T[n][k] = bf16 of gW1[k*256 + n]
__global__ __launch_bounds__(256) void prep_kernel(
    const float* __restrict__ gW0, const float* __restrict__ gW1,
    unsigned short* __restrict__ W0T, unsigned short* __restrict__ W1T)
{
  const int t = blockIdx.x * 256 + threadIdx.x;  // 0..65535
  {
    const int c = t >> 7, k = t & 127;
    const int src = (k + ((c >= 256) ? 128 : 0)) * 256 + (c & 255);
    W0T[t] = f2bf_rne(gW0[src]);
  }
  {
    const int n = t >> 8, k = t & 255;
    W1T[t] = f2bf_rne(gW1[k * 256 + n]);
  }
}

// ---- main: per-batch pair MLP + pooled sum -> d_ws ----
__global__ __launch_bounds__(256, 2) void pair_kernel(
    const float* __restrict__ state,
    const unsigned short* __restrict__ W0T, const float* __restrict__ gb0,
    const unsigned short* __restrict__ W1T, const float* __restrict__ gb1,
    float* __restrict__ pooled)
{
  const int b   = blockIdx.x;
  const int tid = threadIdx.x;
  const int w   = tid >> 6;   // wave 0..3
  const int l   = tid & 63;
  const int lr  = l & 15;
  const int lg  = l >> 4;

  __shared__ float A_lds[16 * LSTR];
  __shared__ float C_lds[16 * LSTR];

  const float* stb = state + (size_t)b * 2048;

  // ---------------- Phase 2: [A|C] = state[16x128] @ W0 ----------------
  short8 sfrag[4];
  #pragma unroll
  for (int kk = 0; kk < 4; ++kk) {
    const float* sp = stb + lr * 128 + kk * 32 + lg * 8;
    f32x4 s0 = *(const f32x4*)sp;
    f32x4 s1 = *(const f32x4*)(sp + 4);
    short8 f;
    f[0] = bfc(s0[0]); f[1] = bfc(s0[1]); f[2] = bfc(s0[2]); f[3] = bfc(s0[3]);
    f[4] = bfc(s1[0]); f[5] = bfc(s1[1]); f[6] = bfc(s1[2]); f[7] = bfc(s1[3]);
    sfrag[kk] = f;
  }

  const f32x4 z4 = {0.f, 0.f, 0.f, 0.f};
  f32x4 acc2[8];
  #pragma unroll
  for (int nt = 0; nt < 8; ++nt) acc2[nt] = z4;

  #pragma unroll
  for (int nt = 0; nt < 8; ++nt) {
    const int col = 128 * w + 16 * nt + lr;       // [A|C] col in [0,512)
    #pragma unroll
    for (int kk = 0; kk < 4; ++kk) {
      short8 bf = *(const short8*)(W0T + (size_t)col * 128 + kk * 32 + lg * 8);
      acc2[nt] = __builtin_amdgcn_mfma_f32_16x16x32_bf16(sfrag[kk], bf, acc2[nt], 0, 0, 0);
    }
  }

  // gW1 fragments: wave w owns N-cols [64w, 64w+64); coalesced bf16 16B loads
  short8 bw[4][8];
  #pragma unroll
  for (int nt = 0; nt < 4; ++nt) {
    const int n = 64 * w + 16 * nt + lr;
    #pragma unroll
    for (int kk = 0; kk < 8; ++kk)
      bw[nt][kk] = *(const short8*)(W1T + (size_t)n * 256 + kk * 32 + lg * 8);
  }
  float gb1v[4];
  #pragma unroll
  for (int nt = 0; nt < 4; ++nt) gb1v[nt] = gb1[64 * w + 16 * nt + lr];

  // store phase-2 results (C/D layout: col=lr, row=lg*4+r)
  #pragma unroll
  for (int nt = 0; nt < 8; ++nt) {
    const int col = 128 * w + 16 * nt + lr;
    #pragma unroll
    for (int r = 0; r < 4; ++r) {
      const int row = lg * 4 + r;
      float v = acc2[nt][r];
      if (col < 256) A_lds[row * LSTR + col]       = v + gb0[col];  // fold gb0
      else           C_lds[row * LSTR + col - 256] = v;
    }
  }
  __syncthreads();

  // C register cache: lane's A-operand rows are j = lr for ALL tiles -> invariant
  f32x4 creg[16];
  #pragma unroll
  for (int kk = 0; kk < 8; ++kk) {
    const float* cp = &C_lds[lr * LSTR + kk * 32 + lg * 8];
    creg[2 * kk]     = *(const f32x4*)cp;
    creg[2 * kk + 1] = *(const f32x4*)(cp + 4);
  }

  // ---------------- Phase 3: tile = fixed i, rows = j (mask j==i) ----------------
  float pooled_part[4] = {0.f, 0.f, 0.f, 0.f};
  #pragma unroll 1
  for (int i = 0; i < 16; ++i) {
    f32x4 acc[4];
    #pragma unroll
    for (int nt = 0; nt < 4; ++nt) acc[nt] = z4;

    #pragma unroll
    for (int kk = 0; kk < 8; ++kk) {
      const float* ap = &A_lds[i * LSTR + kk * 32 + lg * 8];  // wave-uniform bcast
      f32x4 a0 = *(const f32x4*)ap;
      f32x4 a1 = *(const f32x4*)(ap + 4);
      f32x4 s0 = __builtin_elementwise_max(a0 + creg[2 * kk],     z4);
      f32x4 s1 = __builtin_elementwise_max(a1 + creg[2 * kk + 1], z4);
      short8 u;
      u[0] = bfc(s0[0]); u[1] = bfc(s0[1]); u[2] = bfc(s0[2]); u[3] = bfc(s0[3]);
      u[4] = bfc(s1[0]); u[5] = bfc(s1[1]); u[6] = bfc(s1[2]); u[7] = bfc(s1[3]);
      #pragma unroll
      for (int nt = 0; nt < 4; ++nt)
        acc[nt] = __builtin_amdgcn_mfma_f32_16x16x32_bf16(u, bw[nt][kk], acc[nt], 0, 0, 0);
    }

    #pragma unroll
    for (int nt = 0; nt < 4; ++nt) {
      #pragma unroll
      for (int r = 0; r < 4; ++r) {
        const int row = lg * 4 + r;       // = j
        const float v = fmaxf(acc[nt][r] + gb1v[nt], 0.f);
        pooled_part[nt] += (row == i) ? 0.f : v;   // skip the (i,i) filler pair
      }
    }
  }

  // reduce the 4 lane-groups (disjoint row subsets, same col), write pooled
  #pragma unroll
  for (int nt = 0; nt < 4; ++nt) {
    float v = pooled_part[nt];
    v += __shfl_xor(v, 16);
    v += __shfl_xor(v, 32);
    if (lg == 0) pooled[(size_t)b * 256 + 64 * w + 16 * nt + lr] = v;
  }
}

// ---- f-MLP: 8 batches per block -> 8x weight reuse per load ----
__global__ __launch_bounds__(256) void fmlp_kernel(
    const float* __restrict__ pooled,
    const float* __restrict__ fW0, const float* __restrict__ fb0,
    const float* __restrict__ fW1, const float* __restrict__ fb1,
    float* __restrict__ out)
{
  const int tid = threadIdx.x;
  const size_t b0 = (size_t)blockIdx.x * 8;
  __shared__ float pl[8][256];
  __shared__ float h1[8][256];

  #pragma unroll
  for (int q = 0; q < 8; ++q) {
    const int idx = q * 256 + tid;
    pl[idx >> 8][idx & 255] = pooled[b0 * 256 + idx];
  }
  __syncthreads();

  float acc[8] = {0.f, 0.f, 0.f, 0.f, 0.f, 0.f, 0.f, 0.f};
  #pragma unroll 4
  for (int k = 0; k < 256; ++k) {
    const float wv = fW0[(size_t)k * 256 + tid];
    #pragma unroll
    for (int q = 0; q < 8; ++q) acc[q] = fmaf(pl[q][k], wv, acc[q]);
  }
  #pragma unroll
  for (int q = 0; q < 8; ++q) h1[q][tid] = fmaxf(acc[q] + fb0[tid], 0.f);
  __syncthreads();

  float acc2[8] = {0.f, 0.f, 0.f, 0.f, 0.f, 0.f, 0.f, 0.f};
  #pragma unroll 4
  for (int k = 0; k < 256; ++k) {
    const float wv = fW1[(size_t)k * 256 + tid];
    #pragma unroll
    for (int q = 0; q < 8; ++q) acc2[q] = fmaf(h1[q][k], wv, acc2[q]);
  }
  #pragma unroll
  for (int q = 0; q < 8; ++q)
    out[(b0 + q) * 256 + tid] = fmaxf(acc2[q] + fb1[tid], 0.f);
}

extern "C" void kernel_launch(void* const* d_in, const int* in_sizes, int n_in,
                              void* d_out, int out_size, void* d_ws, size_t ws_size,
                              hipStream_t stream) {
  const float* state = (const float*)d_in[0];
  const float* gW0   = (const float*)d_in[1];
  const float* gb0   = (const float*)d_in[2];
  const float* gW1   = (const float*)d_in[3];
  const float* gb1   = (const float*)d_in[4];
  const float* fW0   = (const float*)d_in[5];
  const float* fb0   = (const float*)d_in[6];
  const float* fW1   = (const float*)d_in[7];
  const float* fb1   = (const float*)d_in[8];
  float* out = (float*)d_out;

  unsigned short* W0T = (unsigned short*)d_ws;          // 512*128 bf16 = 128KB
  unsigned short* W1T = W0T + 512 * 128;                // 256*256 bf16 = 128KB
  float* pooled = (float*)(W1T + 256 * 256);            // 1024*256 f32 = 1MB

  const int Bn = in_sizes[0] / 2048;  // 1024

  prep_kernel<<<dim3(256), dim3(256), 0, stream>>>(gW0, gW1, W0T, W1T);
  pair_kernel<<<dim3(Bn), dim3(256), 0, stream>>>(state, W0T, gb0, W1T, gb1, pooled);
  fmlp_kernel<<<dim3(Bn / 8), dim3(256), 0, stream>>>(pooled, fW0, fb0, fW1, fb1, out);
}

// Round 3
// 97.800 us; speedup vs baseline: 1.0572x; 1.0361x over previous
//
#include <hip/hip_runtime.h>
#include <hip/hip_bf16.h>

typedef __attribute__((ext_vector_type(8))) short short8;
typedef __attribute__((ext_vector_type(4))) float f32x4;

#define LSTR 268  // f32 row stride for A/C: 1072B rows, 16B-aligned, <=2-way banks

__device__ __forceinline__ unsigned short f2bf_rne(float x) {
  unsigned u = __float_as_uint(x);
  return (unsigned short)((u + 0x7FFFu + ((u >> 16) & 1u)) >> 16);
}

// scalar cast that the compiler fuses into v_cvt_pk_bf16_f32 pairs (m240)
__device__ __forceinline__ short bfc(float x) {
  __hip_bfloat16 h = __float2bfloat16(x);
  return __builtin_bit_cast(short, h);
}

// ---- prep: weights -> bf16, fragment-transposed into d_ws (once per launch) ----
__global__ __launch_bounds__(256) void prep_kernel(
    const float* __restrict__ gW0, const float* __restrict__ gW1,
    unsigned short* __restrict__ W0T, unsigned short* __restrict__ W1T)
{
  const int t = blockIdx.x * 256 + threadIdx.x;  // 0..65535
  {
    const int c = t >> 7, k = t & 127;
    const int src = (k + ((c >= 256) ? 128 : 0)) * 256 + (c & 255);
    W0T[t] = f2bf_rne(gW0[src]);
  }
  {
    const int n = t >> 8, k = t & 255;
    W1T[t] = f2bf_rne(gW1[k * 256 + n]);
  }
}

// ---- main: per-batch pair MLP + pooled sum ----
// Phase 3 is producer/consumer: per round, wave w builds the bf16 u-tile for
// i = 4r+w in LDS (MFMA A-fragment layout, XOR-swizzled); after a barrier all
// waves run a pure fragment-GEMM over the 4 tiles (no VALU in the MFMA chain).
__global__ __launch_bounds__(256, 2) void pair_kernel(
    const float* __restrict__ state,
    const unsigned short* __restrict__ W0T, const float* __restrict__ gb0,
    const unsigned short* __restrict__ W1T, const float* __restrict__ gb1,
    float* __restrict__ pooled)
{
  const int b   = blockIdx.x;
  const int tid = threadIdx.x;
  const int w   = tid >> 6;   // wave 0..3
  const int l   = tid & 63;
  const int lr  = l & 15;
  const int lg  = l >> 4;

  // A: [16][LSTR] f32 (17152 B). C: same, overlaid by ubuf (4 x 8192 B) after creg.
  __shared__ __align__(16) char smem[17152 + 32768];
  float* A_lds = (float*)smem;
  float* C_lds = (float*)(smem + 17152);
  char*  ubuf  = smem + 17152;

  const float* stb = state + (size_t)b * 2048;

  // ---------------- Phase 2: [A|C] = state[16x128] @ W0 ----------------
  short8 sfrag[4];
  #pragma unroll
  for (int kk = 0; kk < 4; ++kk) {
    const float* sp = stb + lr * 128 + kk * 32 + lg * 8;
    f32x4 s0 = *(const f32x4*)sp;
    f32x4 s1 = *(const f32x4*)(sp + 4);
    short8 f;
    f[0] = bfc(s0[0]); f[1] = bfc(s0[1]); f[2] = bfc(s0[2]); f[3] = bfc(s0[3]);
    f[4] = bfc(s1[0]); f[5] = bfc(s1[1]); f[6] = bfc(s1[2]); f[7] = bfc(s1[3]);
    sfrag[kk] = f;
  }

  const f32x4 z4 = {0.f, 0.f, 0.f, 0.f};
  f32x4 acc2[8];
  #pragma unroll
  for (int nt = 0; nt < 8; ++nt) acc2[nt] = z4;

  #pragma unroll
  for (int nt = 0; nt < 8; ++nt) {
    const int col = 128 * w + 16 * nt + lr;       // [A|C] col in [0,512)
    #pragma unroll
    for (int kk = 0; kk < 4; ++kk) {
      short8 bf = *(const short8*)(W0T + (size_t)col * 128 + kk * 32 + lg * 8);
      acc2[nt] = __builtin_amdgcn_mfma_f32_16x16x32_bf16(sfrag[kk], bf, acc2[nt], 0, 0, 0);
    }
  }

  // gW1 fragments (wave w owns N-cols [64w,64w+64)): issue early, coalesced
  short8 bw[4][8];
  #pragma unroll
  for (int nt = 0; nt < 4; ++nt) {
    const int n = 64 * w + 16 * nt + lr;
    #pragma unroll
    for (int kk = 0; kk < 8; ++kk)
      bw[nt][kk] = *(const short8*)(W1T + (size_t)n * 256 + kk * 32 + lg * 8);
  }
  float gb1v[4];
  #pragma unroll
  for (int nt = 0; nt < 4; ++nt) gb1v[nt] = gb1[64 * w + 16 * nt + lr];

  // store phase-2 results (C/D layout: col=lr, row=lg*4+r)
  #pragma unroll
  for (int nt = 0; nt < 8; ++nt) {
    const int col = 128 * w + 16 * nt + lr;
    #pragma unroll
    for (int r = 0; r < 4; ++r) {
      const int row = lg * 4 + r;
      float v = acc2[nt][r];
      if (col < 256) A_lds[row * LSTR + col]       = v + gb0[col];  // fold gb0
      else           C_lds[row * LSTR + col - 256] = v;
    }
  }
  __syncthreads();

  // C rows -> registers: lane (lr,lg) holds C[lr][kk*32+lg*8 .. +8] for kk=0..7
  f32x4 creg[16];
  #pragma unroll
  for (int kk = 0; kk < 8; ++kk) {
    const float* cp = &C_lds[lr * LSTR + kk * 32 + lg * 8];
    creg[2 * kk]     = *(const f32x4*)cp;
    creg[2 * kk + 1] = *(const f32x4*)(cp + 4);
  }
  __syncthreads();  // all creg captured; ubuf may now overwrite C region

  // per-lane swizzled LDS offset for u fragments (row=lr, k0=kk*32+lg*8)
  const int ulane = lr * 512 + ((lg * 16) ^ ((lr & 7) << 4));

  float pp[4] = {0.f, 0.f, 0.f, 0.f};

  #pragma unroll 1
  for (int r = 0; r < 4; ++r) {
    // ---- produce: wave w builds u-tile for i = 4r+w ----
    const int ip = 4 * r + w;
    #pragma unroll
    for (int kk = 0; kk < 8; ++kk) {
      const float* ap = &A_lds[ip * LSTR + kk * 32 + lg * 8];  // wave-uniform bcast
      f32x4 a0 = *(const f32x4*)ap;
      f32x4 a1 = *(const f32x4*)(ap + 4);
      f32x4 s0 = __builtin_elementwise_max(a0 + creg[2 * kk],     z4);
      f32x4 s1 = __builtin_elementwise_max(a1 + creg[2 * kk + 1], z4);
      short8 u;
      u[0] = bfc(s0[0]); u[1] = bfc(s0[1]); u[2] = bfc(s0[2]); u[3] = bfc(s0[3]);
      u[4] = bfc(s1[0]); u[5] = bfc(s1[1]); u[6] = bfc(s1[2]); u[7] = bfc(s1[3]);
      *(short8*)(ubuf + w * 8192 + (ulane ^ (kk * 64))) = u;
    }
    __syncthreads();  // all 4 u-tiles ready

    // ---- consume: fragment-GEMM over the 4 tiles ----
    #pragma unroll
    for (int i2 = 0; i2 < 4; ++i2) {
      const int i = 4 * r + i2;
      f32x4 acc[4];
      #pragma unroll
      for (int nt = 0; nt < 4; ++nt) acc[nt] = z4;

      #pragma unroll
      for (int kk = 0; kk < 8; ++kk) {
        short8 uf = *(const short8*)(ubuf + i2 * 8192 + (ulane ^ (kk * 64)));
        #pragma unroll
        for (int nt = 0; nt < 4; ++nt)
          acc[nt] = __builtin_amdgcn_mfma_f32_16x16x32_bf16(uf, bw[nt][kk], acc[nt], 0, 0, 0);
      }

      #pragma unroll
      for (int nt = 0; nt < 4; ++nt) {
        #pragma unroll
        for (int r4 = 0; r4 < 4; ++r4) {
          const int row = lg * 4 + r4;       // = j
          const float v = fmaxf(acc[nt][r4] + gb1v[nt], 0.f);
          pp[nt] += (row == i) ? 0.f : v;    // mask the (i,i) filler pair
        }
      }
    }
    __syncthreads();  // tiles consumed; next round may overwrite
  }

  // reduce the 4 lane-groups (disjoint row subsets, same col), write pooled
  #pragma unroll
  for (int nt = 0; nt < 4; ++nt) {
    float v = pp[nt];
    v += __shfl_xor(v, 16);
    v += __shfl_xor(v, 32);
    if (lg == 0) pooled[(size_t)b * 256 + 64 * w + 16 * nt + lr] = v;
  }
}

// ---- f-MLP: 8 batches per block -> 8x weight reuse per load ----
__global__ __launch_bounds__(256) void fmlp_kernel(
    const float* __restrict__ pooled,
    const float* __restrict__ fW0, const float* __restrict__ fb0,
    const float* __restrict__ fW1, const float* __restrict__ fb1,
    float* __restrict__ out)
{
  const int tid = threadIdx.x;
  const size_t b0 = (size_t)blockIdx.x * 8;
  __shared__ float pl[8][256];
  __shared__ float h1[8][256];

  #pragma unroll
  for (int q = 0; q < 8; ++q) {
    const int idx = q * 256 + tid;
    pl[idx >> 8][idx & 255] = pooled[b0 * 256 + idx];
  }
  __syncthreads();

  float acc[8] = {0.f, 0.f, 0.f, 0.f, 0.f, 0.f, 0.f, 0.f};
  #pragma unroll 4
  for (int k = 0; k < 256; ++k) {
    const float wv = fW0[(size_t)k * 256 + tid];
    #pragma unroll
    for (int q = 0; q < 8; ++q) acc[q] = fmaf(pl[q][k], wv, acc[q]);
  }
  #pragma unroll
  for (int q = 0; q < 8; ++q) h1[q][tid] = fmaxf(acc[q] + fb0[tid], 0.f);
  __syncthreads();

  float acc2[8] = {0.f, 0.f, 0.f, 0.f, 0.f, 0.f, 0.f, 0.f};
  #pragma unroll 4
  for (int k = 0; k < 256; ++k) {
    const float wv = fW1[(size_t)k * 256 + tid];
    #pragma unroll
    for (int q = 0; q < 8; ++q) acc2[q] = fmaf(h1[q][k], wv, acc2[q]);
  }
  #pragma unroll
  for (int q = 0; q < 8; ++q)
    out[(b0 + q) * 256 + tid] = fmaxf(acc2[q] + fb1[tid], 0.f);
}

extern "C" void kernel_launch(void* const* d_in, const int* in_sizes, int n_in,
                              void* d_out, int out_size, void* d_ws, size_t ws_size,
                              hipStream_t stream) {
  const float* state = (const float*)d_in[0];
  const float* gW0   = (const float*)d_in[1];
  const float* gb0   = (const float*)d_in[2];
  const float* gW1   = (const float*)d_in[3];
  const float* gb1   = (const float*)d_in[4];
  const float* fW0   = (const float*)d_in[5];
  const float* fb0   = (const float*)d_in[6];
  const float* fW1   = (const float*)d_in[7];
  const float* fb1   = (const float*)d_in[8];
  float* out = (float*)d_out;

  unsigned short* W0T = (unsigned short*)d_ws;          // 512*128 bf16 = 128KB
  unsigned short* W1T = W0T + 512 * 128;                // 256*256 bf16 = 128KB
  float* pooled = (float*)(W1T + 256 * 256);            // 1024*256 f32 = 1MB

  const int Bn = in_sizes[0] / 2048;  // 1024

  prep_kernel<<<dim3(256), dim3(256), 0, stream>>>(gW0, gW1, W0T, W1T);
  pair_kernel<<<dim3(Bn), dim3(256), 0, stream>>>(state, W0T, gb0, W1T, gb1, pooled);
  fmlp_kernel<<<dim3(Bn / 8), dim3(256), 0, stream>>>(pooled, fW0, fb0, fW1, fb1, out);
}